// Round 19
// baseline (139.833 us; speedup 1.0000x reference)
//
#include <hip/hip_runtime.h>
#include <hip/hip_bf16.h>
#include <math.h>

typedef __attribute__((ext_vector_type(8))) short s8;
typedef __attribute__((ext_vector_type(8))) unsigned short us8;
typedef __attribute__((ext_vector_type(4))) unsigned short us4;
typedef __attribute__((ext_vector_type(4))) float f4;

__device__ __forceinline__ unsigned short f2bf(float f) {
    unsigned int u = __float_as_uint(f);
    unsigned int r = u + 0x7FFFu + ((u >> 16) & 1u);   // RNE (no NaNs here)
    return (unsigned short)(r >> 16);
}

__device__ __forceinline__ float softplus_f(float x) {
    return (x > 0.f) ? x + log1pf(expf(-x)) : log1pf(expf(x));
}

// ============ fused: W->W^T bf16 prep + NIG gate + H->bf16 copy ============
__global__ __launch_bounds__(256) void prep_nig_kernel(
        const float* __restrict__ W0, const float* __restrict__ W1,
        const float* __restrict__ W2, const float* __restrict__ W3,
        unsigned short* __restrict__ Wt,
        const float* __restrict__ H_D, const int* __restrict__ maskD,
        const float* __restrict__ H_P, const int* __restrict__ maskP,
        const float* __restrict__ nw, const float* __restrict__ nb,
        float* __restrict__ gpreD, float* __restrict__ gpreP,
        float* __restrict__ abD, float* __restrict__ abP,
        unsigned short* __restrict__ hdb, unsigned short* __restrict__ hpb) {
    int bx = blockIdx.x;
    if (bx < 256) {                       // weight transpose tiles
        __shared__ float t[32][33];
        int wsel = bx >> 6, tile = bx & 63;
        const float* W = wsel == 0 ? W0 : wsel == 1 ? W1 : wsel == 2 ? W2 : W3;
        unsigned short* O = Wt + wsel * 65536;
        int k0 = (tile >> 3) * 32, n0 = (tile & 7) * 32;
        int r = threadIdx.x >> 5, c = threadIdx.x & 31;
#pragma unroll
        for (int i = 0; i < 4; ++i) t[r + i * 8][c] = W[(k0 + r + i * 8) * 256 + n0 + c];
        __syncthreads();
#pragma unroll
        for (int i = 0; i < 4; ++i) O[(n0 + r + i * 8) * 256 + k0 + c] = f2bf(t[c][r + i * 8]);
        return;
    }
    // NIG gate: 4 waves/block, one row each; also emit bf16 row copy
    int row = (bx - 256) * 4 + (threadIdx.x >> 6);
    int lane = threadIdx.x & 63;
    const float* H; const int* mask; float* gpre; float* ab; unsigned short* hb; int lr;
    if (row < 4096) { H = H_D; mask = maskD; gpre = gpreD; ab = abD; hb = hdb; lr = row; }
    else            { H = H_P; mask = maskP; gpre = gpreP; ab = abP; hb = hpb; lr = row - 4096; }
    float4 hv = *(const float4*)(H + (size_t)lr * 256 + lane * 4);
    us4 h4 = { f2bf(hv.x), f2bf(hv.y), f2bf(hv.z), f2bf(hv.w) };
    *(us4*)&hb[(size_t)lr * 256 + lane * 4] = h4;
    float4 n0v = *(const float4*)&nw[(lane * 4 + 0) * 4];
    float4 n1v = *(const float4*)&nw[(lane * 4 + 1) * 4];
    float4 n2v = *(const float4*)&nw[(lane * 4 + 2) * 4];
    float4 n3v = *(const float4*)&nw[(lane * 4 + 3) * 4];
    float a1 = hv.x * n0v.y + hv.y * n1v.y + hv.z * n2v.y + hv.w * n3v.y;
    float a2 = hv.x * n0v.z + hv.y * n1v.z + hv.z * n2v.z + hv.w * n3v.z;
    float a3 = hv.x * n0v.w + hv.y * n1v.w + hv.z * n2v.w + hv.w * n3v.w;
#pragma unroll
    for (int o = 32; o; o >>= 1) {
        a1 += __shfl_xor(a1, o);
        a2 += __shfl_xor(a2, o);
        a3 += __shfl_xor(a3, o);
    }
    if (lane == 0) {
        float nu = softplus_f(a1 + nb[1]);
        float sa = softplus_f(a2 + nb[2]);          // alpha - 1
        float beta = softplus_f(a3 + nb[3]);
        float s2 = beta / (nu * sa + 1e-6f);
        float g = expf(-4.f * s2);
        g = fminf(fmaxf(g, 1e-4f), 1.f);
        gpre[lr] = (mask[lr] != 0) ? g : 0.f;
        ab[lr] = (1.f + sa) + beta;                 // alpha + beta (no atomic)
    }
}

// ============ 128x128 GEMM tile with LDS-staged B (double-buffered) ========
__device__ __forceinline__ void gemm128x128_lds(
        const unsigned short* __restrict__ Ab, const unsigned short* __restrict__ Wp,
        const float* __restrict__ bias, unsigned short* __restrict__ Cb,
        int idx, unsigned short (*bpan)[5120]) {
    const int tid = threadIdx.x, wid = tid >> 6, lane = tid & 63;
    const int g = lane >> 4, lo = lane & 15;
    const size_t row0 = (size_t)(idx >> 1) * 128 + wid * 32;
    const int n0 = (idx & 1) * 128;
    const int c0 = tid >> 2, q0 = tid & 3;
    const unsigned short* gp0 = Wp + (size_t)(n0 + c0) * 256 + q0 * 8;
    const unsigned short* gp1 = Wp + (size_t)(n0 + c0 + 64) * 256 + q0 * 8;
    const int l0 = c0 * 40 + q0 * 8;
    const int l1 = (c0 + 64) * 40 + q0 * 8;
    const unsigned short* ap0 = Ab + (row0 + lo) * 256 + g * 8;
    const unsigned short* ap1 = Ab + (row0 + 16 + lo) * 256 + g * 8;

    f4 acc[2][8];
#pragma unroll
    for (int a = 0; a < 2; ++a)
#pragma unroll
        for (int f = 0; f < 8; ++f) acc[a][f] = (f4){0.f, 0.f, 0.f, 0.f};

    *(us8*)&bpan[0][l0] = *(const us8*)gp0;
    *(us8*)&bpan[0][l1] = *(const us8*)gp1;
    s8 av0 = *(const s8*)ap0;
    s8 av1 = *(const s8*)ap1;

    for (int t = 0; t < 8; ++t) {
        const int buf = t & 1;
        us8 pn0, pn1; s8 an0, an1;
        if (t < 7) {
            pn0 = *(const us8*)(gp0 + (t + 1) * 32);
            pn1 = *(const us8*)(gp1 + (t + 1) * 32);
            an0 = *(const s8*)(ap0 + (t + 1) * 32);
            an1 = *(const s8*)(ap1 + (t + 1) * 32);
        }
        __syncthreads();
#pragma unroll
        for (int f = 0; f < 8; ++f) {
            s8 bfr = *(const s8*)&bpan[buf][(f * 16 + lo) * 40 + g * 8];
            acc[0][f] = __builtin_amdgcn_mfma_f32_16x16x32_bf16(av0, bfr, acc[0][f], 0, 0, 0);
            acc[1][f] = __builtin_amdgcn_mfma_f32_16x16x32_bf16(av1, bfr, acc[1][f], 0, 0, 0);
        }
        if (t < 7) {
            *(us8*)&bpan[buf ^ 1][l0] = pn0;
            *(us8*)&bpan[buf ^ 1][l1] = pn1;
            av0 = an0;
            av1 = an1;
        }
    }
#pragma unroll
    for (int a = 0; a < 2; ++a)
#pragma unroll
        for (int f = 0; f < 8; ++f) {
            int col = n0 + f * 16 + lo;
            float bv2 = bias[col];
#pragma unroll
            for (int r = 0; r < 4; ++r)
                Cb[(row0 + a * 16 + g * 4 + r) * 256 + col] = f2bf(acc[a][f][r] + bv2);
        }
}

// ============ 64x128 GEMM tile (kv2 keeps this: 256-block coverage) ========
__device__ __forceinline__ void gemm64x128_lds(
        const unsigned short* __restrict__ Ab, const unsigned short* __restrict__ Wp,
        const float* __restrict__ bias, unsigned short* __restrict__ Cb,
        int idx, unsigned short (*bpan)[5120]) {
    const int tid = threadIdx.x, wid = tid >> 6, lane = tid & 63;
    const int g = lane >> 4, lo = lane & 15;
    const size_t row0 = (size_t)(idx >> 1) * 64 + wid * 16;
    const int n0 = (idx & 1) * 128;
    const int c0 = tid >> 2, q0 = tid & 3;
    const unsigned short* gp0 = Wp + (size_t)(n0 + c0) * 256 + q0 * 8;
    const unsigned short* gp1 = Wp + (size_t)(n0 + c0 + 64) * 256 + q0 * 8;
    const int l0 = c0 * 40 + q0 * 8;
    const int l1 = (c0 + 64) * 40 + q0 * 8;
    const unsigned short* ap = Ab + (row0 + lo) * 256 + g * 8;

    f4 acc[8];
#pragma unroll
    for (int f = 0; f < 8; ++f) acc[f] = (f4){0.f, 0.f, 0.f, 0.f};

    *(us8*)&bpan[0][l0] = *(const us8*)gp0;
    *(us8*)&bpan[0][l1] = *(const us8*)gp1;
    s8 av = *(const s8*)ap;

    for (int t = 0; t < 8; ++t) {
        const int buf = t & 1;
        us8 pn0, pn1; s8 avn;
        if (t < 7) {
            pn0 = *(const us8*)(gp0 + (t + 1) * 32);
            pn1 = *(const us8*)(gp1 + (t + 1) * 32);
            avn = *(const s8*)(ap + (t + 1) * 32);
        }
        __syncthreads();
#pragma unroll
        for (int f = 0; f < 8; ++f) {
            s8 bfr = *(const s8*)&bpan[buf][(f * 16 + lo) * 40 + g * 8];
            acc[f] = __builtin_amdgcn_mfma_f32_16x16x32_bf16(av, bfr, acc[f], 0, 0, 0);
        }
        if (t < 7) {
            *(us8*)&bpan[buf ^ 1][l0] = pn0;
            *(us8*)&bpan[buf ^ 1][l1] = pn1;
            av = avn;
        }
    }
#pragma unroll
    for (int f = 0; f < 8; ++f) {
        int col = n0 + f * 16 + lo;
        float bv2 = bias[col];
#pragma unroll
        for (int r = 0; r < 4; ++r)
            Cb[(row0 + g * 4 + r) * 256 + col] = f2bf(acc[f][r] + bv2);
    }
}

// ============ per-batch top-k body (partial sums to dedicated slots) =======
__device__ __forceinline__ void topk_body(
        const float* __restrict__ gpre, const int* __restrict__ mask,
        float* __restrict__ gout, float* __restrict__ logg,
        float* __restrict__ sgArr, float* __restrict__ smArr,
        int N, int b, int by, int bslot, float* grow, float* red) {
    int tid = threadIdx.x;
    int j = by * 256 + tid;
    for (int i = tid; i < N; i += 256) grow[i] = gpre[b * N + i];
    float cpart = 0.f;
    for (int i = tid; i < N; i += 256) cpart += (mask[b * N + i] != 0) ? 1.f : 0.f;
    red[tid] = cpart;
    __syncthreads();
    for (int s = 128; s; s >>= 1) { if (tid < s) red[tid] += red[tid + s]; __syncthreads(); }
    float count = red[0];
    __syncthreads();
    int k = (int)fmaxf(count * 0.5f, 1.0f);
    float gj = grow[j];
    int rank = 0;
    for (int i = 0; i < N; ++i) {
        float gi = grow[i];
        rank += (gi > gj || (gi == gj && i < j)) ? 1 : 0;
    }
    float gf = (rank < k) ? gj : 0.f;
    gout[b * N + j] = gf;
    logg[b * N + j] = logf(gf + 1e-8f);
    red[tid] = gf;
    __syncthreads();
    for (int s = 128; s; s >>= 1) { if (tid < s) red[tid] += red[tid + s]; __syncthreads(); }
    if (tid == 0) sgArr[bslot] = red[0];
    __syncthreads();
    red[tid] = (mask[b * N + j] != 0) ? 1.f : 0.f;
    __syncthreads();
    for (int s = 128; s; s >>= 1) { if (tid < s) red[tid] += red[tid + s]; __syncthreads(); }
    if (tid == 0) smArr[bslot] = red[0];
}

// ============ mega launch: q1,k1,v1,q2 projections + topk + EDL reduce =====
__global__ __launch_bounds__(256) void qkv_topk_kernel(
        const unsigned short* __restrict__ hdb, const unsigned short* __restrict__ hpb,
        const unsigned short* __restrict__ Wt,
        const float* __restrict__ bq, const float* __restrict__ bk, const float* __restrict__ bv,
        unsigned short* __restrict__ q1b, unsigned short* __restrict__ k1b,
        unsigned short* __restrict__ v1b, unsigned short* __restrict__ q2b,
        const float* __restrict__ gpreD, const int* __restrict__ maskD,
        float* __restrict__ goutD, float* __restrict__ loggD,
        const float* __restrict__ gpreP, const int* __restrict__ maskP,
        float* __restrict__ goutP, float* __restrict__ loggP,
        float* __restrict__ sgD, float* __restrict__ smD,
        float* __restrict__ sgP, float* __restrict__ smP,
        const float* __restrict__ abD, const float* __restrict__ abP,
        float* __restrict__ edl2) {
    __shared__ unsigned short bpan[2][5120];     // 20.5 KB (aliased by topk)
    int bx = blockIdx.x;
    int tid = threadIdx.x;
    if (bx == 496) {                      // EDL sums
        float* red = (float*)&bpan[0][0];
        float s1 = 0.f, s2 = 0.f;
        for (int i = tid; i < 4096; i += 256) s1 += abD[i];
        for (int i = tid; i < 8192; i += 256) s2 += abP[i];
        red[tid] = s1;
        __syncthreads();
        for (int s = 128; s; s >>= 1) { if (tid < s) red[tid] += red[tid + s]; __syncthreads(); }
        if (tid == 0) edl2[0] = red[0];
        __syncthreads();
        red[tid] = s2;
        __syncthreads();
        for (int s = 128; s; s >>= 1) { if (tid < s) red[tid] += red[tid + s]; __syncthreads(); }
        if (tid == 0) edl2[1] = red[0];
        return;
    }
    if (bx >= 448) {                      // top-k (48 blocks)
        float* grow = (float*)&bpan[0][0];
        float* red = grow + 1024;
        int tb = bx - 448;
        int b = tb & 7, by = tb >> 3;
        if (by < 2) topk_body(gpreD, maskD, goutD, loggD, sgD, smD, 512, b, by, b * 2 + by, grow, red);
        else        topk_body(gpreP, maskP, goutP, loggP, sgP, smP, 1024, b, by - 2, b * 4 + (by - 2), grow, red);
        return;
    }
    // QKV projections (bf16 A, LDS-staged B, 128-row tiles)
    const unsigned short* Ab; const unsigned short* Wp; const float* bias;
    unsigned short* Cb; int idx;
    if (bx < 64)       { Ab = hdb; Wp = Wt;          bias = bq; Cb = q1b; idx = bx; }
    else if (bx < 192) { Ab = hpb; Wp = Wt + 65536;  bias = bk; Cb = k1b; idx = bx - 64; }
    else if (bx < 320) { Ab = hpb; Wp = Wt + 131072; bias = bv; Cb = v1b; idx = bx - 192; }
    else               { Ab = hpb; Wp = Wt;          bias = bq; Cb = q2b; idx = bx - 320; }
    gemm128x128_lds(Ab, Wp, bias, Cb, idx, bpan);
}

// ============ k2,v2 projections from bf16 Xd in one launch =================
__global__ __launch_bounds__(256) void kv2_mega_kernel(
        const unsigned short* __restrict__ xdb, const unsigned short* __restrict__ Wt,
        const float* __restrict__ bk, const float* __restrict__ bv,
        unsigned short* __restrict__ k2b, unsigned short* __restrict__ v2b) {
    __shared__ unsigned short bpan[2][5120];
    int bx = blockIdx.x;
    const unsigned short* Wp; const float* bias; unsigned short* Cb; int idx;
    if (bx < 128) { Wp = Wt + 65536;  bias = bk; Cb = k2b; idx = bx; }
    else          { Wp = Wt + 131072; bias = bv; Cb = v2b; idx = bx - 128; }
    gemm64x128_lds(xdb, Wp, bias, Cb, idx, bpan);
}

// ============ Wo GEMM + bias + residual + LayerNorm ========================
__global__ __launch_bounds__(256) void gemm_o_ln_kernel(
        const unsigned short* __restrict__ A, const unsigned short* __restrict__ Wt,
        const float* __restrict__ bias, const float* __restrict__ resid,
        const float* __restrict__ gam, const float* __restrict__ bet,
        float* __restrict__ Out, unsigned short* __restrict__ OutB,
        const float* __restrict__ sgD, const float* __restrict__ smD,
        const float* __restrict__ sgP, const float* __restrict__ smP,
        const float* __restrict__ edl2, float* __restrict__ lossOut) {
    __shared__ float sums[4][16], sqs[4][16];
    const int tid = threadIdx.x, wid = tid >> 6, lane = tid & 63;
    const int g = lane >> 4, lo = lane & 15;
    const size_t row0 = (size_t)blockIdx.x * 16;
    const int c0 = wid * 64;
    f4 acc[4];
#pragma unroll
    for (int f = 0; f < 4; ++f) acc[f] = (f4){0.f, 0.f, 0.f, 0.f};
    for (int k0 = 0; k0 < 256; k0 += 32) {
        s8 af = *(const s8*)&A[(row0 + lo) * 256 + k0 + g * 8];
#pragma unroll
        for (int f = 0; f < 4; ++f) {
            s8 bfr = *(const s8*)&Wt[(size_t)(c0 + f * 16 + lo) * 256 + k0 + g * 8];
            acc[f] = __builtin_amdgcn_mfma_f32_16x16x32_bf16(af, bfr, acc[f], 0, 0, 0);
        }
    }
#pragma unroll
    for (int r = 0; r < 4; ++r) {
        size_t row = row0 + g * 4 + r;
        float sv = 0.f, qv = 0.f;
#pragma unroll
        for (int f = 0; f < 4; ++f) {
            int col = c0 + f * 16 + lo;
            float v = acc[f][r] + bias[col] + resid[row * 256 + col];
            acc[f][r] = v;
            sv += v;
            qv += v * v;
        }
#pragma unroll
        for (int o = 1; o < 16; o <<= 1) { sv += __shfl_xor(sv, o); qv += __shfl_xor(qv, o); }
        if (lo == 0) { sums[wid][g * 4 + r] = sv; sqs[wid][g * 4 + r] = qv; }
    }
    __syncthreads();
#pragma unroll
    for (int r = 0; r < 4; ++r) {
        int rl = g * 4 + r;
        size_t row = row0 + rl;
        float st = sums[0][rl] + sums[1][rl] + sums[2][rl] + sums[3][rl];
        float qt = sqs[0][rl] + sqs[1][rl] + sqs[2][rl] + sqs[3][rl];
        float mean = st * (1.f / 256.f);
        float var = qt * (1.f / 256.f) - mean * mean;
        float inv = rsqrtf(var + 1e-5f);
#pragma unroll
        for (int f = 0; f < 4; ++f) {
            int col = c0 + f * 16 + lo;
            float y = (acc[f][r] - mean) * inv * gam[col] + bet[col];
            Out[row * 256 + col] = y;
            if (OutB) OutB[row * 256 + col] = f2bf(y);
        }
    }
    // scalar loss fold (block 0, wave 0; inputs ready dispatches earlier)
    if (lossOut && blockIdx.x == 0 && tid < 64) {
        float sgd = 0.f, smd = 0.f, sgp = 0.f, smp = 0.f;
        if (lane < 16) { sgd = sgD[lane]; smd = smD[lane]; }
        if (lane < 32) { sgp = sgP[lane]; smp = smP[lane]; }
#pragma unroll
        for (int o = 16; o; o >>= 1) { sgp += __shfl_xor(sgp, o); smp += __shfl_xor(smp, o); }
#pragma unroll
        for (int o = 8; o; o >>= 1) { sgd += __shfl_xor(sgd, o); smd += __shfl_xor(smd, o); }
        if (lane == 0) {
            float t1 = sgd / (smd + 1e-8f) - 0.3f;
            float t2 = sgp / (smp + 1e-8f) - 0.3f;
            lossOut[0] = 0.01f * (t1 * t1) + 0.01f * (t2 * t2)
                       + 1e-3f * (edl2[0] / 4096.f) + 1e-3f * (edl2[1] / 8192.f);
        }
    }
}

// ============ fused flash attention: 128-key tiles, 32 q-rows per wave =====
// Each wave owns 2 Q-frags processed sequentially per tile (VGPR-friendly).
template <int NK>
__global__ __launch_bounds__(256) void attn_mfma_kernel(
        const unsigned short* __restrict__ qb, const unsigned short* __restrict__ kb,
        const unsigned short* __restrict__ vb, const float* __restrict__ logg,
        unsigned short* __restrict__ ctxb, int Nq) {
    __shared__ unsigned short Kf[2][4096];    // K-frags: [ks(8)][lane(64)][8]
    __shared__ unsigned short Vf[2][4096];    // V-frags: [kh*2+dh (8)][lane][8]
    __shared__ unsigned short Pf[4][2176];    // per-wave P: [16 q][136 pitch]
    __shared__ float lg[2][128];
    constexpr int NT = NK / 128;

    const int tid = threadIdx.x;
    const int wid = tid >> 6, lane = tid & 63;
    const int g = lane >> 4, lo = lane & 15;
    const int b = blockIdx.y >> 3, h = blockIdx.y & 7;
    const int q0 = blockIdx.x * 128 + wid * 32;
    const size_t bq = (size_t)b * Nq, bk = (size_t)b * NK;
    const float scale = 0.17677669529663687f;  // 1/sqrt(32)

    const int kloc = tid >> 2, quad = tid & 3;
    const size_t gbase = (bk + kloc) * 256 + h * 32 + quad * 8;
    const int kfa = ((kloc >> 4) << 9) + (quad * 16 + (kloc & 15)) * 8;   // +2048 for row+64
    const int vkh = kloc >> 5, vgg = (kloc >> 3) & 3, vj = kloc & 7;
    const int vdh = quad >> 1, vl0 = (quad & 1) * 8;
    const int vb0 = ((vkh * 2 + vdh) << 9) + vgg * 128 + vj;              // +2048 for row+64

    s8 qf0 = *(const s8*)&qb[(bq + q0 + lo) * 256 + h * 32 + g * 8];
    s8 qf1 = *(const s8*)&qb[(bq + q0 + 16 + lo) * 256 + h * 32 + g * 8];

    f4 o00 = {0.f,0.f,0.f,0.f}, o01 = {0.f,0.f,0.f,0.f};
    f4 o10 = {0.f,0.f,0.f,0.f}, o11 = {0.f,0.f,0.f,0.f};
    float mrow[2][4], lsum[2][4];
#pragma unroll
    for (int qr = 0; qr < 2; ++qr)
#pragma unroll
        for (int r = 0; r < 4; ++r) { mrow[qr][r] = -3e38f; lsum[qr][r] = 0.f; }

    // prologue: tile 0 -> regs -> LDS[0]
    us8 krA = *(const us8*)&kb[gbase];
    us8 krB = *(const us8*)&kb[gbase + 64 * 256];
    us8 vrA = *(const us8*)&vb[gbase];
    us8 vrB = *(const us8*)&vb[gbase + 64 * 256];
    float lgreg = (tid < 128) ? logg[bk + tid] : 0.f;
    *(us8*)&Kf[0][kfa] = krA;
    *(us8*)&Kf[0][kfa + 2048] = krB;
#pragma unroll
    for (int jj = 0; jj < 8; ++jj) {
        Vf[0][vb0 + (vl0 + jj) * 8] = vrA[jj];
        Vf[0][vb0 + 2048 + (vl0 + jj) * 8] = vrB[jj];
    }
    if (tid < 128) lg[0][tid] = lgreg;

    for (int t = 0; t < NT; ++t) {
        const int cur = t & 1;
        if (t + 1 < NT) {                 // issue next tile's global loads early
            size_t ga = gbase + (size_t)(t + 1) * 128 * 256;
            krA = *(const us8*)&kb[ga];
            krB = *(const us8*)&kb[ga + 64 * 256];
            vrA = *(const us8*)&vb[ga];
            vrB = *(const us8*)&vb[ga + 64 * 256];
            if (tid < 128) lgreg = logg[bk + (t + 1) * 128 + tid];
        }
        __syncthreads();                  // LDS[cur] ready for all waves

#pragma unroll
        for (int qr = 0; qr < 2; ++qr) {
            s8 qf = qr ? qf1 : qf0;
            // ---- scores: 8 MFMAs over 128 keys ----
            f4 sc[8];
#pragma unroll
            for (int ks = 0; ks < 8; ++ks) {
                s8 kfr = *(const s8*)&Kf[cur][(ks << 9) + lane * 8];
                f4 z = {0.f, 0.f, 0.f, 0.f};
                f4 s4 = __builtin_amdgcn_mfma_f32_16x16x32_bf16(qf, kfr, z, 0, 0, 0);
                float lga = lg[cur][ks * 16 + lo];
#pragma unroll
                for (int r = 0; r < 4; ++r) sc[ks][r] = s4[r] * scale + lga;
            }
            // ---- online softmax ----
            float vm[4];
#pragma unroll
            for (int r = 0; r < 4; ++r) {
                float m0 = fmaxf(fmaxf(sc[0][r], sc[1][r]), fmaxf(sc[2][r], sc[3][r]));
                float m1 = fmaxf(fmaxf(sc[4][r], sc[5][r]), fmaxf(sc[6][r], sc[7][r]));
                vm[r] = fmaxf(m0, m1);
            }
#pragma unroll
            for (int off = 1; off < 16; off <<= 1)
#pragma unroll
                for (int r = 0; r < 4; ++r) vm[r] = fmaxf(vm[r], __shfl_xor(vm[r], off));
            float al[4], ps[4];
#pragma unroll
            for (int r = 0; r < 4; ++r) {
                float mn = fmaxf(mrow[qr][r], vm[r]);
                al[r] = __expf(mrow[qr][r] - mn);
                mrow[qr][r] = mn;
                ps[r] = 0.f;
            }
#pragma unroll
            for (int ks = 0; ks < 8; ++ks)
#pragma unroll
                for (int r = 0; r < 4; ++r) {
                    float p = __expf(sc[ks][r] - mrow[qr][r]);
                    ps[r] += p;
                    Pf[wid][(g * 4 + r) * 136 + ks * 16 + lo] = f2bf(p);
                }
#pragma unroll
            for (int off = 1; off < 16; off <<= 1)
#pragma unroll
                for (int r = 0; r < 4; ++r) ps[r] += __shfl_xor(ps[r], off);
#pragma unroll
            for (int r = 0; r < 4; ++r) {
                lsum[qr][r] = lsum[qr][r] * al[r] + ps[r];
                if (qr == 0) { o00[r] *= al[r]; o01[r] *= al[r]; }
                else         { o10[r] *= al[r]; o11[r] *= al[r]; }
            }
            // ---- PV: 8 MFMAs (4 k-halves x 2 d-halves) ----
#pragma unroll
            for (int kh = 0; kh < 4; ++kh) {
                s8 pfr = *(const s8*)&Pf[wid][lo * 136 + kh * 32 + g * 8];
                s8 vf0 = *(const s8*)&Vf[cur][((kh * 2 + 0) << 9) + lane * 8];
                s8 vf1 = *(const s8*)&Vf[cur][((kh * 2 + 1) << 9) + lane * 8];
                if (qr == 0) {
                    o00 = __builtin_amdgcn_mfma_f32_16x16x32_bf16(pfr, vf0, o00, 0, 0, 0);
                    o01 = __builtin_amdgcn_mfma_f32_16x16x32_bf16(pfr, vf1, o01, 0, 0, 0);
                } else {
                    o10 = __builtin_amdgcn_mfma_f32_16x16x32_bf16(pfr, vf0, o10, 0, 0, 0);
                    o11 = __builtin_amdgcn_mfma_f32_16x16x32_bf16(pfr, vf1, o11, 0, 0, 0);
                }
            }
        }
        // ---- write next tile regs -> LDS[cur^1] ----
        if (t + 1 < NT) {
            const int nxt = cur ^ 1;
            *(us8*)&Kf[nxt][kfa] = krA;
            *(us8*)&Kf[nxt][kfa + 2048] = krB;
#pragma unroll
            for (int jj = 0; jj < 8; ++jj) {
                Vf[nxt][vb0 + (vl0 + jj) * 8] = vrA[jj];
                Vf[nxt][vb0 + 2048 + (vl0 + jj) * 8] = vrB[jj];
            }
            if (tid < 128) lg[nxt][tid] = lgreg;
        }
    }
    // ---- epilogue (bf16 ctx) ----
#pragma unroll
    for (int r = 0; r < 4; ++r) {
        float inv0 = 1.f / lsum[0][r];
        unsigned short* cp0 = ctxb + (bq + q0 + g * 4 + r) * 256 + h * 32;
        cp0[lo] = f2bf(o00[r] * inv0);
        cp0[16 + lo] = f2bf(o01[r] * inv0);
        float inv1 = 1.f / lsum[1][r];
        unsigned short* cp1 = ctxb + (bq + q0 + 16 + g * 4 + r) * 256 + h * 32;
        cp1[lo] = f2bf(o10[r] * inv1);
        cp1[16 + lo] = f2bf(o11[r] * inv1);
    }
}

extern "C" void kernel_launch(void* const* d_in, const int* in_sizes, int n_in,
                              void* d_out, int out_size, void* d_ws, size_t ws_size,
                              hipStream_t stream) {
    (void)in_sizes; (void)n_in; (void)out_size; (void)ws_size;
    const float* H_D   = (const float*)d_in[0];
    const int*   maskD = (const int*)d_in[1];
    const float* H_P   = (const float*)d_in[2];
    const int*   maskP = (const int*)d_in[3];
    const float* nig_w = (const float*)d_in[4];
    const float* nig_b = (const float*)d_in[5];
    const float* Wq = (const float*)d_in[6];
    const float* bq = (const float*)d_in[7];
    const float* Wk = (const float*)d_in[8];
    const float* bk = (const float*)d_in[9];
    const float* Wv = (const float*)d_in[10];
    const float* bv = (const float*)d_in[11];
    const float* Wo = (const float*)d_in[12];
    const float* bo = (const float*)d_in[13];
    const float* ln_g = (const float*)d_in[14];
    const float* ln_b = (const float*)d_in[15];
    float* out = (float*)d_out;
    float* ws = (float*)d_ws;

    // output offsets (f32): Xd, Xp, g_D, g_P, loss
    float* outXd = out + 0;
    float* outXp = out + 1048576;
    float* outGD = out + 3145728;
    float* outGP = out + 3149824;
    float* outLo = out + 3158016;

    // f32 workspace (all written deterministically every call — no memset)
    float* abD   = ws;               // 4096
    float* abP   = ws + 4096;        // 8192
    float* sgD   = ws + 12288;       // 16
    float* smD   = ws + 12304;       // 16
    float* sgP   = ws + 12320;       // 32
    float* smP   = ws + 12352;       // 32
    float* edl2  = ws + 12384;       // 2
    float* gpreD = ws + 12416;       // 4096
    float* gpreP = ws + 16512;       // 8192
    float* logD  = ws + 24704;       // 4096
    float* logP  = ws + 28800;       // 8192
    // bf16 workspace (starts at float offset 36992, 16B aligned)
    unsigned short* ub  = (unsigned short*)(ws + 36992);
    unsigned short* Wt  = ub;                    // 4 x 65536
    unsigned short* q1b = ub + 262144;           // 1M
    unsigned short* k1b = ub + 1310720;          // 2M
    unsigned short* v1b = ub + 3407872;          // 2M
    unsigned short* q2b = ub + 5505024;          // 2M (live through phase 1)
    unsigned short* c1b = ub + 7602176;          // 1M
    unsigned short* xdb = ub + 8650752;          // 1M
    unsigned short* k2b = ub + 9699328;          // 1M
    unsigned short* v2b = ub + 10747904;         // 1M
    unsigned short* c2b = ub + 11796480;         // 2M
    // bf16 H copies: dead after dispatch 2 — alias late-phase buffers
    unsigned short* hdb = c1b;                   // 1M (c1b written at dispatch 3)
    unsigned short* hpb = xdb;                   // 2M (xdb/k2b written at 4/5)

    // 1) weight prep + NIG gates + H->bf16
    prep_nig_kernel<<<3328, 256, 0, stream>>>(Wq, Wk, Wv, Wo, Wt,
                                              H_D, maskD, H_P, maskP,
                                              nig_w, nig_b, gpreD, gpreP, abD, abP,
                                              hdb, hpb);
    // 2) q1,k1,v1,q2 projections (128-row tiles) + top-k + EDL (one launch)
    qkv_topk_kernel<<<497, 256, 0, stream>>>(hdb, hpb, Wt, bq, bk, bv,
                                             q1b, k1b, v1b, q2b,
                                             gpreD, maskD, outGD, logD,
                                             gpreP, maskP, outGP, logP,
                                             sgD, smD, sgP, smP, abD, abP, edl2);
    // 3) MHCA1 attention (128-key tiles, 128 q-rows/block)
    attn_mfma_kernel<1024><<<dim3(4, 64), 256, 0, stream>>>(q1b, k1b, v1b, logP, c1b, 512);
    // 4) Wo+LN (f32 Xd to d_out + bf16 copy)
    gemm_o_ln_kernel<<<256, 256, 0, stream>>>(c1b, Wt + 3 * 65536, bo, H_D, ln_g, ln_b,
                                              outXd, xdb, nullptr, nullptr, nullptr, nullptr,
                                              nullptr, nullptr);
    // 5) k2,v2 projections
    kv2_mega_kernel<<<256, 256, 0, stream>>>(xdb, Wt, bk, bv, k2b, v2b);
    // 6) MHCA2 attention (128-key tiles, 128 q-rows/block)
    attn_mfma_kernel<512><<<dim3(8, 64), 256, 0, stream>>>(q2b, k2b, v2b, logD, c2b, 1024);
    // 7) Wo+LN + scalar loss
    gemm_o_ln_kernel<<<512, 256, 0, stream>>>(c2b, Wt + 3 * 65536, bo, H_P, ln_g, ln_b,
                                              outXp, nullptr, sgD, smD, sgP, smP, edl2, outLo);
}

// Round 20
// 128.999 us; speedup vs baseline: 1.0840x; 1.0840x over previous
//
#include <hip/hip_runtime.h>
#include <hip/hip_bf16.h>
#include <math.h>

typedef __attribute__((ext_vector_type(8))) short s8;
typedef __attribute__((ext_vector_type(8))) unsigned short us8;
typedef __attribute__((ext_vector_type(4))) unsigned short us4;
typedef __attribute__((ext_vector_type(4))) float f4;

__device__ __forceinline__ unsigned short f2bf(float f) {
    unsigned int u = __float_as_uint(f);
    unsigned int r = u + 0x7FFFu + ((u >> 16) & 1u);   // RNE (no NaNs here)
    return (unsigned short)(r >> 16);
}

__device__ __forceinline__ float softplus_f(float x) {
    return (x > 0.f) ? x + log1pf(expf(-x)) : log1pf(expf(x));
}

// ============ fused: W->W^T bf16 prep + NIG gate + H->bf16 copy ============
__global__ __launch_bounds__(256) void prep_nig_kernel(
        const float* __restrict__ W0, const float* __restrict__ W1,
        const float* __restrict__ W2, const float* __restrict__ W3,
        unsigned short* __restrict__ Wt,
        const float* __restrict__ H_D, const int* __restrict__ maskD,
        const float* __restrict__ H_P, const int* __restrict__ maskP,
        const float* __restrict__ nw, const float* __restrict__ nb,
        float* __restrict__ gpreD, float* __restrict__ gpreP,
        float* __restrict__ abD, float* __restrict__ abP,
        unsigned short* __restrict__ hdb, unsigned short* __restrict__ hpb) {
    int bx = blockIdx.x;
    if (bx < 256) {                       // weight transpose tiles
        __shared__ float t[32][33];
        int wsel = bx >> 6, tile = bx & 63;
        const float* W = wsel == 0 ? W0 : wsel == 1 ? W1 : wsel == 2 ? W2 : W3;
        unsigned short* O = Wt + wsel * 65536;
        int k0 = (tile >> 3) * 32, n0 = (tile & 7) * 32;
        int r = threadIdx.x >> 5, c = threadIdx.x & 31;
#pragma unroll
        for (int i = 0; i < 4; ++i) t[r + i * 8][c] = W[(k0 + r + i * 8) * 256 + n0 + c];
        __syncthreads();
#pragma unroll
        for (int i = 0; i < 4; ++i) O[(n0 + r + i * 8) * 256 + k0 + c] = f2bf(t[c][r + i * 8]);
        return;
    }
    // NIG gate: 4 waves/block, one row each; also emit bf16 row copy
    int row = (bx - 256) * 4 + (threadIdx.x >> 6);
    int lane = threadIdx.x & 63;
    const float* H; const int* mask; float* gpre; float* ab; unsigned short* hb; int lr;
    if (row < 4096) { H = H_D; mask = maskD; gpre = gpreD; ab = abD; hb = hdb; lr = row; }
    else            { H = H_P; mask = maskP; gpre = gpreP; ab = abP; hb = hpb; lr = row - 4096; }
    float4 hv = *(const float4*)(H + (size_t)lr * 256 + lane * 4);
    us4 h4 = { f2bf(hv.x), f2bf(hv.y), f2bf(hv.z), f2bf(hv.w) };
    *(us4*)&hb[(size_t)lr * 256 + lane * 4] = h4;
    float4 n0v = *(const float4*)&nw[(lane * 4 + 0) * 4];
    float4 n1v = *(const float4*)&nw[(lane * 4 + 1) * 4];
    float4 n2v = *(const float4*)&nw[(lane * 4 + 2) * 4];
    float4 n3v = *(const float4*)&nw[(lane * 4 + 3) * 4];
    float a1 = hv.x * n0v.y + hv.y * n1v.y + hv.z * n2v.y + hv.w * n3v.y;
    float a2 = hv.x * n0v.z + hv.y * n1v.z + hv.z * n2v.z + hv.w * n3v.z;
    float a3 = hv.x * n0v.w + hv.y * n1v.w + hv.z * n2v.w + hv.w * n3v.w;
#pragma unroll
    for (int o = 32; o; o >>= 1) {
        a1 += __shfl_xor(a1, o);
        a2 += __shfl_xor(a2, o);
        a3 += __shfl_xor(a3, o);
    }
    if (lane == 0) {
        float nu = softplus_f(a1 + nb[1]);
        float sa = softplus_f(a2 + nb[2]);          // alpha - 1
        float beta = softplus_f(a3 + nb[3]);
        float s2 = beta / (nu * sa + 1e-6f);
        float g = expf(-4.f * s2);
        g = fminf(fmaxf(g, 1e-4f), 1.f);
        gpre[lr] = (mask[lr] != 0) ? g : 0.f;
        ab[lr] = (1.f + sa) + beta;                 // alpha + beta (no atomic)
    }
}

// ============ 128x128 GEMM tile with LDS-staged B (double-buffered) ========
__device__ __forceinline__ void gemm128x128_lds(
        const unsigned short* __restrict__ Ab, const unsigned short* __restrict__ Wp,
        const float* __restrict__ bias, unsigned short* __restrict__ Cb,
        int idx, unsigned short (*bpan)[5120]) {
    const int tid = threadIdx.x, wid = tid >> 6, lane = tid & 63;
    const int g = lane >> 4, lo = lane & 15;
    const size_t row0 = (size_t)(idx >> 1) * 128 + wid * 32;
    const int n0 = (idx & 1) * 128;
    const int c0 = tid >> 2, q0 = tid & 3;
    const unsigned short* gp0 = Wp + (size_t)(n0 + c0) * 256 + q0 * 8;
    const unsigned short* gp1 = Wp + (size_t)(n0 + c0 + 64) * 256 + q0 * 8;
    const int l0 = c0 * 40 + q0 * 8;
    const int l1 = (c0 + 64) * 40 + q0 * 8;
    const unsigned short* ap0 = Ab + (row0 + lo) * 256 + g * 8;
    const unsigned short* ap1 = Ab + (row0 + 16 + lo) * 256 + g * 8;

    f4 acc[2][8];
#pragma unroll
    for (int a = 0; a < 2; ++a)
#pragma unroll
        for (int f = 0; f < 8; ++f) acc[a][f] = (f4){0.f, 0.f, 0.f, 0.f};

    *(us8*)&bpan[0][l0] = *(const us8*)gp0;
    *(us8*)&bpan[0][l1] = *(const us8*)gp1;
    s8 av0 = *(const s8*)ap0;
    s8 av1 = *(const s8*)ap1;

    for (int t = 0; t < 8; ++t) {
        const int buf = t & 1;
        us8 pn0, pn1; s8 an0, an1;
        if (t < 7) {
            pn0 = *(const us8*)(gp0 + (t + 1) * 32);
            pn1 = *(const us8*)(gp1 + (t + 1) * 32);
            an0 = *(const s8*)(ap0 + (t + 1) * 32);
            an1 = *(const s8*)(ap1 + (t + 1) * 32);
        }
        __syncthreads();
#pragma unroll
        for (int f = 0; f < 8; ++f) {
            s8 bfr = *(const s8*)&bpan[buf][(f * 16 + lo) * 40 + g * 8];
            acc[0][f] = __builtin_amdgcn_mfma_f32_16x16x32_bf16(av0, bfr, acc[0][f], 0, 0, 0);
            acc[1][f] = __builtin_amdgcn_mfma_f32_16x16x32_bf16(av1, bfr, acc[1][f], 0, 0, 0);
        }
        if (t < 7) {
            *(us8*)&bpan[buf ^ 1][l0] = pn0;
            *(us8*)&bpan[buf ^ 1][l1] = pn1;
            av0 = an0;
            av1 = an1;
        }
    }
#pragma unroll
    for (int a = 0; a < 2; ++a)
#pragma unroll
        for (int f = 0; f < 8; ++f) {
            int col = n0 + f * 16 + lo;
            float bv2 = bias[col];
#pragma unroll
            for (int r = 0; r < 4; ++r)
                Cb[(row0 + a * 16 + g * 4 + r) * 256 + col] = f2bf(acc[a][f][r] + bv2);
        }
}

// ============ 64x128 GEMM tile (kv2 keeps this: 256-block coverage) ========
__device__ __forceinline__ void gemm64x128_lds(
        const unsigned short* __restrict__ Ab, const unsigned short* __restrict__ Wp,
        const float* __restrict__ bias, unsigned short* __restrict__ Cb,
        int idx, unsigned short (*bpan)[5120]) {
    const int tid = threadIdx.x, wid = tid >> 6, lane = tid & 63;
    const int g = lane >> 4, lo = lane & 15;
    const size_t row0 = (size_t)(idx >> 1) * 64 + wid * 16;
    const int n0 = (idx & 1) * 128;
    const int c0 = tid >> 2, q0 = tid & 3;
    const unsigned short* gp0 = Wp + (size_t)(n0 + c0) * 256 + q0 * 8;
    const unsigned short* gp1 = Wp + (size_t)(n0 + c0 + 64) * 256 + q0 * 8;
    const int l0 = c0 * 40 + q0 * 8;
    const int l1 = (c0 + 64) * 40 + q0 * 8;
    const unsigned short* ap = Ab + (row0 + lo) * 256 + g * 8;

    f4 acc[8];
#pragma unroll
    for (int f = 0; f < 8; ++f) acc[f] = (f4){0.f, 0.f, 0.f, 0.f};

    *(us8*)&bpan[0][l0] = *(const us8*)gp0;
    *(us8*)&bpan[0][l1] = *(const us8*)gp1;
    s8 av = *(const s8*)ap;

    for (int t = 0; t < 8; ++t) {
        const int buf = t & 1;
        us8 pn0, pn1; s8 avn;
        if (t < 7) {
            pn0 = *(const us8*)(gp0 + (t + 1) * 32);
            pn1 = *(const us8*)(gp1 + (t + 1) * 32);
            avn = *(const s8*)(ap + (t + 1) * 32);
        }
        __syncthreads();
#pragma unroll
        for (int f = 0; f < 8; ++f) {
            s8 bfr = *(const s8*)&bpan[buf][(f * 16 + lo) * 40 + g * 8];
            acc[f] = __builtin_amdgcn_mfma_f32_16x16x32_bf16(av, bfr, acc[f], 0, 0, 0);
        }
        if (t < 7) {
            *(us8*)&bpan[buf ^ 1][l0] = pn0;
            *(us8*)&bpan[buf ^ 1][l1] = pn1;
            av = avn;
        }
    }
#pragma unroll
    for (int f = 0; f < 8; ++f) {
        int col = n0 + f * 16 + lo;
        float bv2 = bias[col];
#pragma unroll
        for (int r = 0; r < 4; ++r)
            Cb[(row0 + g * 4 + r) * 256 + col] = f2bf(acc[f][r] + bv2);
    }
}

// ============ per-batch top-k body (partial sums to dedicated slots) =======
__device__ __forceinline__ void topk_body(
        const float* __restrict__ gpre, const int* __restrict__ mask,
        float* __restrict__ gout, float* __restrict__ logg,
        float* __restrict__ sgArr, float* __restrict__ smArr,
        int N, int b, int by, int bslot, float* grow, float* red) {
    int tid = threadIdx.x;
    int j = by * 256 + tid;
    for (int i = tid; i < N; i += 256) grow[i] = gpre[b * N + i];
    float cpart = 0.f;
    for (int i = tid; i < N; i += 256) cpart += (mask[b * N + i] != 0) ? 1.f : 0.f;
    red[tid] = cpart;
    __syncthreads();
    for (int s = 128; s; s >>= 1) { if (tid < s) red[tid] += red[tid + s]; __syncthreads(); }
    float count = red[0];
    __syncthreads();
    int k = (int)fmaxf(count * 0.5f, 1.0f);
    float gj = grow[j];
    int rank = 0;
    for (int i = 0; i < N; ++i) {
        float gi = grow[i];
        rank += (gi > gj || (gi == gj && i < j)) ? 1 : 0;
    }
    float gf = (rank < k) ? gj : 0.f;
    gout[b * N + j] = gf;
    logg[b * N + j] = logf(gf + 1e-8f);
    red[tid] = gf;
    __syncthreads();
    for (int s = 128; s; s >>= 1) { if (tid < s) red[tid] += red[tid + s]; __syncthreads(); }
    if (tid == 0) sgArr[bslot] = red[0];
    __syncthreads();
    red[tid] = (mask[b * N + j] != 0) ? 1.f : 0.f;
    __syncthreads();
    for (int s = 128; s; s >>= 1) { if (tid < s) red[tid] += red[tid + s]; __syncthreads(); }
    if (tid == 0) smArr[bslot] = red[0];
}

// ============ mega launch: q1,k1,v1,q2 projections + topk + EDL reduce =====
__global__ __launch_bounds__(256) void qkv_topk_kernel(
        const unsigned short* __restrict__ hdb, const unsigned short* __restrict__ hpb,
        const unsigned short* __restrict__ Wt,
        const float* __restrict__ bq, const float* __restrict__ bk, const float* __restrict__ bv,
        unsigned short* __restrict__ q1b, unsigned short* __restrict__ k1b,
        unsigned short* __restrict__ v1b, unsigned short* __restrict__ q2b,
        const float* __restrict__ gpreD, const int* __restrict__ maskD,
        float* __restrict__ goutD, float* __restrict__ loggD,
        const float* __restrict__ gpreP, const int* __restrict__ maskP,
        float* __restrict__ goutP, float* __restrict__ loggP,
        float* __restrict__ sgD, float* __restrict__ smD,
        float* __restrict__ sgP, float* __restrict__ smP,
        const float* __restrict__ abD, const float* __restrict__ abP,
        float* __restrict__ edl2) {
    __shared__ unsigned short bpan[2][5120];     // 20.5 KB (aliased by topk)
    int bx = blockIdx.x;
    int tid = threadIdx.x;
    if (bx == 496) {                      // EDL sums
        float* red = (float*)&bpan[0][0];
        float s1 = 0.f, s2 = 0.f;
        for (int i = tid; i < 4096; i += 256) s1 += abD[i];
        for (int i = tid; i < 8192; i += 256) s2 += abP[i];
        red[tid] = s1;
        __syncthreads();
        for (int s = 128; s; s >>= 1) { if (tid < s) red[tid] += red[tid + s]; __syncthreads(); }
        if (tid == 0) edl2[0] = red[0];
        __syncthreads();
        red[tid] = s2;
        __syncthreads();
        for (int s = 128; s; s >>= 1) { if (tid < s) red[tid] += red[tid + s]; __syncthreads(); }
        if (tid == 0) edl2[1] = red[0];
        return;
    }
    if (bx >= 448) {                      // top-k (48 blocks)
        float* grow = (float*)&bpan[0][0];
        float* red = grow + 1024;
        int tb = bx - 448;
        int b = tb & 7, by = tb >> 3;
        if (by < 2) topk_body(gpreD, maskD, goutD, loggD, sgD, smD, 512, b, by, b * 2 + by, grow, red);
        else        topk_body(gpreP, maskP, goutP, loggP, sgP, smP, 1024, b, by - 2, b * 4 + (by - 2), grow, red);
        return;
    }
    // QKV projections (bf16 A, LDS-staged B, 128-row tiles)
    const unsigned short* Ab; const unsigned short* Wp; const float* bias;
    unsigned short* Cb; int idx;
    if (bx < 64)       { Ab = hdb; Wp = Wt;          bias = bq; Cb = q1b; idx = bx; }
    else if (bx < 192) { Ab = hpb; Wp = Wt + 65536;  bias = bk; Cb = k1b; idx = bx - 64; }
    else if (bx < 320) { Ab = hpb; Wp = Wt + 131072; bias = bv; Cb = v1b; idx = bx - 192; }
    else               { Ab = hpb; Wp = Wt;          bias = bq; Cb = q2b; idx = bx - 320; }
    gemm128x128_lds(Ab, Wp, bias, Cb, idx, bpan);
}

// ============ k2,v2 projections from bf16 Xd in one launch =================
__global__ __launch_bounds__(256) void kv2_mega_kernel(
        const unsigned short* __restrict__ xdb, const unsigned short* __restrict__ Wt,
        const float* __restrict__ bk, const float* __restrict__ bv,
        unsigned short* __restrict__ k2b, unsigned short* __restrict__ v2b) {
    __shared__ unsigned short bpan[2][5120];
    int bx = blockIdx.x;
    const unsigned short* Wp; const float* bias; unsigned short* Cb; int idx;
    if (bx < 128) { Wp = Wt + 65536;  bias = bk; Cb = k2b; idx = bx; }
    else          { Wp = Wt + 131072; bias = bv; Cb = v2b; idx = bx - 128; }
    gemm64x128_lds(xdb, Wp, bias, Cb, idx, bpan);
}

// ============ Wo GEMM + bias + residual + LayerNorm ========================
__global__ __launch_bounds__(256) void gemm_o_ln_kernel(
        const unsigned short* __restrict__ A, const unsigned short* __restrict__ Wt,
        const float* __restrict__ bias, const float* __restrict__ resid,
        const float* __restrict__ gam, const float* __restrict__ bet,
        float* __restrict__ Out, unsigned short* __restrict__ OutB,
        const float* __restrict__ sgD, const float* __restrict__ smD,
        const float* __restrict__ sgP, const float* __restrict__ smP,
        const float* __restrict__ edl2, float* __restrict__ lossOut) {
    __shared__ float sums[4][16], sqs[4][16];
    const int tid = threadIdx.x, wid = tid >> 6, lane = tid & 63;
    const int g = lane >> 4, lo = lane & 15;
    const size_t row0 = (size_t)blockIdx.x * 16;
    const int c0 = wid * 64;
    f4 acc[4];
#pragma unroll
    for (int f = 0; f < 4; ++f) acc[f] = (f4){0.f, 0.f, 0.f, 0.f};
    for (int k0 = 0; k0 < 256; k0 += 32) {
        s8 af = *(const s8*)&A[(row0 + lo) * 256 + k0 + g * 8];
#pragma unroll
        for (int f = 0; f < 4; ++f) {
            s8 bfr = *(const s8*)&Wt[(size_t)(c0 + f * 16 + lo) * 256 + k0 + g * 8];
            acc[f] = __builtin_amdgcn_mfma_f32_16x16x32_bf16(af, bfr, acc[f], 0, 0, 0);
        }
    }
#pragma unroll
    for (int r = 0; r < 4; ++r) {
        size_t row = row0 + g * 4 + r;
        float sv = 0.f, qv = 0.f;
#pragma unroll
        for (int f = 0; f < 4; ++f) {
            int col = c0 + f * 16 + lo;
            float v = acc[f][r] + bias[col] + resid[row * 256 + col];
            acc[f][r] = v;
            sv += v;
            qv += v * v;
        }
#pragma unroll
        for (int o = 1; o < 16; o <<= 1) { sv += __shfl_xor(sv, o); qv += __shfl_xor(qv, o); }
        if (lo == 0) { sums[wid][g * 4 + r] = sv; sqs[wid][g * 4 + r] = qv; }
    }
    __syncthreads();
#pragma unroll
    for (int r = 0; r < 4; ++r) {
        int rl = g * 4 + r;
        size_t row = row0 + rl;
        float st = sums[0][rl] + sums[1][rl] + sums[2][rl] + sums[3][rl];
        float qt = sqs[0][rl] + sqs[1][rl] + sqs[2][rl] + sqs[3][rl];
        float mean = st * (1.f / 256.f);
        float var = qt * (1.f / 256.f) - mean * mean;
        float inv = rsqrtf(var + 1e-5f);
#pragma unroll
        for (int f = 0; f < 4; ++f) {
            int col = c0 + f * 16 + lo;
            float y = (acc[f][r] - mean) * inv * gam[col] + bet[col];
            Out[row * 256 + col] = y;
            if (OutB) OutB[row * 256 + col] = f2bf(y);
        }
    }
    // scalar loss fold (block 0, wave 0; inputs ready dispatches earlier)
    if (lossOut && blockIdx.x == 0 && tid < 64) {
        float sgd = 0.f, smd = 0.f, sgp = 0.f, smp = 0.f;
        if (lane < 16) { sgd = sgD[lane]; smd = smD[lane]; }
        if (lane < 32) { sgp = sgP[lane]; smp = smP[lane]; }
#pragma unroll
        for (int o = 16; o; o >>= 1) { sgp += __shfl_xor(sgp, o); smp += __shfl_xor(smp, o); }
#pragma unroll
        for (int o = 8; o; o >>= 1) { sgd += __shfl_xor(sgd, o); smd += __shfl_xor(smd, o); }
        if (lane == 0) {
            float t1 = sgd / (smd + 1e-8f) - 0.3f;
            float t2 = sgp / (smp + 1e-8f) - 0.3f;
            lossOut[0] = 0.01f * (t1 * t1) + 0.01f * (t2 * t2)
                       + 1e-3f * (edl2[0] / 4096.f) + 1e-3f * (edl2[1] / 8192.f);
        }
    }
}

// ============ fused flash attention: 128-key tiles, 1 barrier per tile =====
template <int NK>
__global__ __launch_bounds__(256) void attn_mfma_kernel(
        const unsigned short* __restrict__ qb, const unsigned short* __restrict__ kb,
        const unsigned short* __restrict__ vb, const float* __restrict__ logg,
        unsigned short* __restrict__ ctxb, int Nq) {
    __shared__ unsigned short Kf[2][4096];    // K-frags: [ks(8)][lane(64)][8]
    __shared__ unsigned short Vf[2][4096];    // V-frags: [kh*2+dh (8)][lane][8]
    __shared__ unsigned short Pf[4][2176];    // per-wave P: [16 q][136 pitch]
    __shared__ float lg[2][128];
    constexpr int NT = NK / 128;

    const int tid = threadIdx.x;
    const int wid = tid >> 6, lane = tid & 63;
    const int g = lane >> 4, lo = lane & 15;
    const int b = blockIdx.y >> 3, h = blockIdx.y & 7;
    const int q0 = blockIdx.x * 64 + wid * 16;
    const size_t bq = (size_t)b * Nq, bk = (size_t)b * NK;
    const float scale = 0.17677669529663687f;  // 1/sqrt(32)

    // staging: thread owns rows kloc and kloc+64 of the 128-row tile
    const int kloc = tid >> 2, quad = tid & 3;
    const size_t gbase = (bk + kloc) * 256 + h * 32 + quad * 8;
    const int kfa = ((kloc >> 4) << 9) + (quad * 16 + (kloc & 15)) * 8;   // +2048 for row+64
    const int vkh = kloc >> 5, vgg = (kloc >> 3) & 3, vj = kloc & 7;
    const int vdh = quad >> 1, vl0 = (quad & 1) * 8;
    const int vb0 = ((vkh * 2 + vdh) << 9) + vgg * 128 + vj;              // +2048 for row+64

    s8 qf = *(const s8*)&qb[(bq + q0 + lo) * 256 + h * 32 + g * 8];

    f4 o0 = {0.f, 0.f, 0.f, 0.f}, o1 = {0.f, 0.f, 0.f, 0.f};
    float mrow[4] = {-3e38f, -3e38f, -3e38f, -3e38f};
    float lsum[4] = {0.f, 0.f, 0.f, 0.f};

    // prologue: tile 0 -> regs -> LDS[0]
    us8 krA = *(const us8*)&kb[gbase];
    us8 krB = *(const us8*)&kb[gbase + 64 * 256];
    us8 vrA = *(const us8*)&vb[gbase];
    us8 vrB = *(const us8*)&vb[gbase + 64 * 256];
    float lgreg = (tid < 128) ? logg[bk + tid] : 0.f;
    *(us8*)&Kf[0][kfa] = krA;
    *(us8*)&Kf[0][kfa + 2048] = krB;
#pragma unroll
    for (int jj = 0; jj < 8; ++jj) {
        Vf[0][vb0 + (vl0 + jj) * 8] = vrA[jj];
        Vf[0][vb0 + 2048 + (vl0 + jj) * 8] = vrB[jj];
    }
    if (tid < 128) lg[0][tid] = lgreg;

    for (int t = 0; t < NT; ++t) {
        const int cur = t & 1;
        if (t + 1 < NT) {                 // issue next tile's global loads early
            size_t ga = gbase + (size_t)(t + 1) * 128 * 256;
            krA = *(const us8*)&kb[ga];
            krB = *(const us8*)&kb[ga + 64 * 256];
            vrA = *(const us8*)&vb[ga];
            vrB = *(const us8*)&vb[ga + 64 * 256];
            if (tid < 128) lgreg = logg[bk + (t + 1) * 128 + tid];
        }
        __syncthreads();                  // LDS[cur] ready for all waves

        // ---- scores: 8 MFMAs over 128 keys ----
        f4 sc[8];
#pragma unroll
        for (int ks = 0; ks < 8; ++ks) {
            s8 kfr = *(const s8*)&Kf[cur][(ks << 9) + lane * 8];
            f4 z = {0.f, 0.f, 0.f, 0.f};
            f4 s4 = __builtin_amdgcn_mfma_f32_16x16x32_bf16(qf, kfr, z, 0, 0, 0);
            float lga = lg[cur][ks * 16 + lo];
#pragma unroll
            for (int r = 0; r < 4; ++r) sc[ks][r] = s4[r] * scale + lga;
        }
        // ---- online softmax ----
        float vm[4];
#pragma unroll
        for (int r = 0; r < 4; ++r) {
            float m0 = fmaxf(fmaxf(sc[0][r], sc[1][r]), fmaxf(sc[2][r], sc[3][r]));
            float m1 = fmaxf(fmaxf(sc[4][r], sc[5][r]), fmaxf(sc[6][r], sc[7][r]));
            vm[r] = fmaxf(m0, m1);
        }
#pragma unroll
        for (int off = 1; off < 16; off <<= 1)
#pragma unroll
            for (int r = 0; r < 4; ++r) vm[r] = fmaxf(vm[r], __shfl_xor(vm[r], off));
        float al[4], ps[4];
#pragma unroll
        for (int r = 0; r < 4; ++r) {
            float mn = fmaxf(mrow[r], vm[r]);
            al[r] = __expf(mrow[r] - mn);
            mrow[r] = mn;
            ps[r] = 0.f;
        }
#pragma unroll
        for (int ks = 0; ks < 8; ++ks)
#pragma unroll
            for (int r = 0; r < 4; ++r) {
                float p = __expf(sc[ks][r] - mrow[r]);
                ps[r] += p;
                Pf[wid][(g * 4 + r) * 136 + ks * 16 + lo] = f2bf(p);
            }
#pragma unroll
        for (int off = 1; off < 16; off <<= 1)
#pragma unroll
            for (int r = 0; r < 4; ++r) ps[r] += __shfl_xor(ps[r], off);
#pragma unroll
        for (int r = 0; r < 4; ++r) {
            lsum[r] = lsum[r] * al[r] + ps[r];
            o0[r] *= al[r];
            o1[r] *= al[r];
        }
        // ---- PV: 8 MFMAs (4 k-halves x 2 d-halves) ----
#pragma unroll
        for (int kh = 0; kh < 4; ++kh) {
            s8 pfr = *(const s8*)&Pf[wid][lo * 136 + kh * 32 + g * 8];
            s8 vf0 = *(const s8*)&Vf[cur][((kh * 2 + 0) << 9) + lane * 8];
            o0 = __builtin_amdgcn_mfma_f32_16x16x32_bf16(pfr, vf0, o0, 0, 0, 0);
            s8 vf1 = *(const s8*)&Vf[cur][((kh * 2 + 1) << 9) + lane * 8];
            o1 = __builtin_amdgcn_mfma_f32_16x16x32_bf16(pfr, vf1, o1, 0, 0, 0);
        }
        // ---- write next tile regs -> LDS[cur^1] ----
        if (t + 1 < NT) {
            const int nxt = cur ^ 1;
            *(us8*)&Kf[nxt][kfa] = krA;
            *(us8*)&Kf[nxt][kfa + 2048] = krB;
#pragma unroll
            for (int jj = 0; jj < 8; ++jj) {
                Vf[nxt][vb0 + (vl0 + jj) * 8] = vrA[jj];
                Vf[nxt][vb0 + 2048 + (vl0 + jj) * 8] = vrB[jj];
            }
            if (tid < 128) lg[nxt][tid] = lgreg;
        }
    }
    // ---- epilogue (bf16 ctx) ----
#pragma unroll
    for (int r = 0; r < 4; ++r) {
        float inv = 1.f / lsum[r];
        unsigned short* cp = ctxb + (bq + q0 + g * 4 + r) * 256 + h * 32;
        cp[lo] = f2bf(o0[r] * inv);
        cp[16 + lo] = f2bf(o1[r] * inv);
    }
}

extern "C" void kernel_launch(void* const* d_in, const int* in_sizes, int n_in,
                              void* d_out, int out_size, void* d_ws, size_t ws_size,
                              hipStream_t stream) {
    (void)in_sizes; (void)n_in; (void)out_size; (void)ws_size;
    const float* H_D   = (const float*)d_in[0];
    const int*   maskD = (const int*)d_in[1];
    const float* H_P   = (const float*)d_in[2];
    const int*   maskP = (const int*)d_in[3];
    const float* nig_w = (const float*)d_in[4];
    const float* nig_b = (const float*)d_in[5];
    const float* Wq = (const float*)d_in[6];
    const float* bq = (const float*)d_in[7];
    const float* Wk = (const float*)d_in[8];
    const float* bk = (const float*)d_in[9];
    const float* Wv = (const float*)d_in[10];
    const float* bv = (const float*)d_in[11];
    const float* Wo = (const float*)d_in[12];
    const float* bo = (const float*)d_in[13];
    const float* ln_g = (const float*)d_in[14];
    const float* ln_b = (const float*)d_in[15];
    float* out = (float*)d_out;
    float* ws = (float*)d_ws;

    // output offsets (f32): Xd, Xp, g_D, g_P, loss
    float* outXd = out + 0;
    float* outXp = out + 1048576;
    float* outGD = out + 3145728;
    float* outGP = out + 3149824;
    float* outLo = out + 3158016;

    // f32 workspace (all written deterministically every call — no memset)
    float* abD   = ws;               // 4096
    float* abP   = ws + 4096;        // 8192
    float* sgD   = ws + 12288;       // 16
    float* smD   = ws + 12304;       // 16
    float* sgP   = ws + 12320;       // 32
    float* smP   = ws + 12352;       // 32
    float* edl2  = ws + 12384;       // 2
    float* gpreD = ws + 12416;       // 4096
    float* gpreP = ws + 16512;       // 8192
    float* logD  = ws + 24704;       // 4096
    float* logP  = ws + 28800;       // 8192
    // bf16 workspace (starts at float offset 36992, 16B aligned)
    unsigned short* ub  = (unsigned short*)(ws + 36992);
    unsigned short* Wt  = ub;                    // 4 x 65536
    unsigned short* q1b = ub + 262144;           // 1M
    unsigned short* k1b = ub + 1310720;          // 2M
    unsigned short* v1b = ub + 3407872;          // 2M
    unsigned short* q2b = ub + 5505024;          // 2M (live through phase 1)
    unsigned short* c1b = ub + 7602176;          // 1M
    unsigned short* xdb = ub + 8650752;          // 1M
    unsigned short* k2b = ub + 9699328;          // 1M
    unsigned short* v2b = ub + 10747904;         // 1M
    unsigned short* c2b = ub + 11796480;         // 2M
    // bf16 H copies: dead after dispatch 2 — alias late-phase buffers
    unsigned short* hdb = c1b;                   // 1M (c1b written at dispatch 3)
    unsigned short* hpb = xdb;                   // 2M (xdb/k2b written at 4/5)

    // 1) weight prep + NIG gates + H->bf16
    prep_nig_kernel<<<3328, 256, 0, stream>>>(Wq, Wk, Wv, Wo, Wt,
                                              H_D, maskD, H_P, maskP,
                                              nig_w, nig_b, gpreD, gpreP, abD, abP,
                                              hdb, hpb);
    // 2) q1,k1,v1,q2 projections (128-row tiles) + top-k + EDL (one launch)
    qkv_topk_kernel<<<497, 256, 0, stream>>>(hdb, hpb, Wt, bq, bk, bv,
                                             q1b, k1b, v1b, q2b,
                                             gpreD, maskD, outGD, logD,
                                             gpreP, maskP, outGP, logP,
                                             sgD, smD, sgP, smP, abD, abP, edl2);
    // 3) MHCA1 attention (128-key tiles)
    attn_mfma_kernel<1024><<<dim3(8, 64), 256, 0, stream>>>(q1b, k1b, v1b, logP, c1b, 512);
    // 4) Wo+LN (f32 Xd to d_out + bf16 copy)
    gemm_o_ln_kernel<<<256, 256, 0, stream>>>(c1b, Wt + 3 * 65536, bo, H_D, ln_g, ln_b,
                                              outXd, xdb, nullptr, nullptr, nullptr, nullptr,
                                              nullptr, nullptr);
    // 5) k2,v2 projections
    kv2_mega_kernel<<<256, 256, 0, stream>>>(xdb, Wt, bk, bv, k2b, v2b);
    // 6) MHCA2 attention (128-key tiles)
    attn_mfma_kernel<512><<<dim3(16, 64), 256, 0, stream>>>(q2b, k2b, v2b, logD, c2b, 1024);
    // 7) Wo+LN + scalar loss
    gemm_o_ln_kernel<<<512, 256, 0, stream>>>(c2b, Wt + 3 * 65536, bo, H_P, ln_g, ln_b,
                                              outXp, nullptr, sgD, smD, sgP, smP, edl2, outLo);
}